// Round 8
// baseline (12281.201 us; speedup 1.0000x reference)
//
#include <hip/hip_runtime.h>
#include <hip/hip_bf16.h>

// Problem constants
#define BATCH 2048
#define NCH 64
#define MAXLEN 128
#define RDIM 256

// Workspace float offsets
#define WCAT_OFF 0        // [256 k][128 up][8] (u0 gates: r,z comb, i_n, h_n | u1 gates)
#define WHH0_OFF 262144   // [256 k][128 up][8] step-0 (hr, hz, hnw, 0)x2
#define WLH_OFF  524288   // [384 k][256 u]
#define WOUT_OFF 622592   // [256 k][64 o] transposed
#define BCAT_OFF 638976   // [256 u][4]
#define BCAT0_OFF 640000  // [256 u][4]

__global__ void prep_kernel(const float* __restrict__ W_lh,
                            const float* __restrict__ W_ih, const float* __restrict__ W_hh,
                            const float* __restrict__ b_ih, const float* __restrict__ b_hh,
                            const float* __restrict__ W_out, float* __restrict__ ws) {
    int gid = blockIdx.x * blockDim.x + threadIdx.x;   // 0..98303
    if (gid < 384 * 256) {
        int k = gid >> 8, u = gid & 255;
        ws[WLH_OFF + gid] = W_lh[u * 384 + k];
    }
    if (gid < 65536) {
        int k = gid >> 8, u = gid & 255;
        float ir = W_ih[u * 256 + k], iz = W_ih[(256 + u) * 256 + k], inw = W_ih[(512 + u) * 256 + k];
        float hr = W_hh[u * 256 + k], hz = W_hh[(256 + u) * 256 + k], hnw = W_hh[(512 + u) * 256 + k];
        int up = u >> 1, half = u & 1;
        int base = WCAT_OFF + (k * 128 + up) * 8 + half * 4;
        ws[base + 0] = ir + hr; ws[base + 1] = iz + hz; ws[base + 2] = inw; ws[base + 3] = hnw;
        base = WHH0_OFF + (k * 128 + up) * 8 + half * 4;
        ws[base + 0] = hr; ws[base + 1] = hz; ws[base + 2] = hnw; ws[base + 3] = 0.0f;
    }
    if (gid < 16384) {
        int o = gid & 63, k = gid >> 6;
        ws[WOUT_OFF + k * 64 + o] = W_out[o * 256 + k];   // [k][o]
    }
    if (gid < 256) {
        int u = gid;
        float bir = b_ih[u], biz = b_ih[256 + u];
        float bhr = b_hh[u], bhz = b_hh[256 + u], bhn = b_hh[512 + u];
        int base = BCAT_OFF + u * 4;
        ws[base + 0] = bir + bhr; ws[base + 1] = biz + bhz; ws[base + 2] = b_ih[512 + u]; ws[base + 3] = bhn;
        base = BCAT0_OFF + u * 4;
        ws[base + 0] = bir + bhr; ws[base + 1] = biz + bhz; ws[base + 2] = bhn; ws[base + 3] = 0.0f;
    }
}

__device__ __forceinline__ float sigm(float x)   { return 1.0f / (1.0f + __expf(-x)); }
__device__ __forceinline__ float tanh_f(float x) { return 1.0f - 2.0f / (1.0f + __expf(2.0f * x)); }

// NOTE: was a macro FMA4(acc,s,w) — macro param `w` collided with member `.w`
// (preprocessor rewrote acc.w -> acc.<arg>). Inline function has no such hazard.
__device__ __forceinline__ void fma4(float4& a, float s, const float4 b) {
    a.x += s * b.x; a.y += s * b.y; a.z += s * b.z; a.w += s * b.w;
}

// 256 wgs x 1024 threads. Thread: up = tid&127 (units 2up,2up+1), rg = (tid>>7)&1
// (rows rg*4..rg*4+3), kg = tid>>8 (k in [kg*64, kg*64+64)).
// Own row (for reduce+epilogue) = rg*4 + kg. acc slot jj <-> local row (kg+jj)&3.
// Weight loads pipelined: B(u1)@k4 at top, A(u0)@k4+1 between FMA half-blocks.
__global__ __launch_bounds__(1024, 1)
void gru_persist(const float* __restrict__ z, const float* __restrict__ xc,
                 const float* __restrict__ b_lh, const float* __restrict__ b_ih,
                 const float* __restrict__ b_out_g,
                 const float* __restrict__ ws, float* __restrict__ out) {
    __shared__ __align__(16) float lds_h[8 * 256];        // 8 KB
    __shared__ __align__(16) float4 pbufv[2 * 12 * 256];  // 96 KB: planeA [0,3072), planeB [3072,6144)
    __shared__ float lbuf[1024];                          // 4 KB

    const int tid = threadIdx.x;
    const int up  = tid & 127;
    const int rg  = __builtin_amdgcn_readfirstlane((tid >> 7) & 1);
    const int kg  = __builtin_amdgcn_readfirstlane(tid >> 8);
    const int b0  = blockIdx.x * 8;
    const int u0  = 2 * up;                 // unit pair
    const int r_own = rg * 4 + kg;          // global own row
    const int col = rg * 128 + up;          // partial-plane column

    // ---- stage zc = [z | x_cond] rows b0..b0+7 into pbufv-as-float [i][384]
    float* zcs = (float*)pbufv;
    for (int idx = tid; idx < 8 * 384; idx += 1024) {
        int i = idx / 384, k = idx - i * 384;
        zcs[idx] = (k < 256) ? z[(b0 + i) * 256 + k] : xc[(b0 + i) * 128 + (k - 256)];
    }
    __syncthreads();

    // ---- h0[r_own][u0], h0[r_own][u1]
    float h_own0, h_own1;
    {
        float a0 = b_lh[u0], a1 = b_lh[u0 + 1];
        const float* Wlh = ws + WLH_OFF + u0;
        const float* zr = zcs + r_own * 384;
#pragma unroll 4
        for (int k = 0; k < 384; ++k) {
            const float2 wv = *(const float2*)&Wlh[k * 256];
            float hvv = zr[k];
            a0 += hvv * wv.x; a1 += hvv * wv.y;
        }
        h_own0 = a0; h_own1 = a1;
        *(float2*)&lds_h[r_own * 256 + u0] = make_float2(a0, a1);
    }
    __syncthreads();   // zc reads done, h0 visible, pbufv free

    const float4  bc1_0 = ((const float4*)(ws + BCAT_OFF))[u0];
    const float4  bc1_1 = ((const float4*)(ws + BCAT_OFF))[u0 + 1];
    const float4  bc0_0 = ((const float4*)(ws + BCAT0_OFF))[u0];
    const float4  bc0_1 = ((const float4*)(ws + BCAT0_OFF))[u0 + 1];
    const float   binc0 = b_ih[512 + u0], binc1 = b_ih[512 + u0 + 1];

    int ro4[4];   // acc slot jj -> LDS row offset of global row rg*4 + ((kg+jj)&3)
#pragma unroll
    for (int jj = 0; jj < 4; ++jj) ro4[jj] = (rg * 4 + ((kg + jj) & 3)) << 8;
    const int kbase = kg * 64;

    // logits mapping (independent of GEMM mapping)
    const int lkh = tid & 1;
    const float* hrow_base = lds_h + ((tid >> 1) >> 6) * 256 + lkh * 128;
    const float* wcolT = ws + WOUT_OFF + lkh * 128 * 64 + ((tid >> 1) & 63);
    const int co = tid & 63, cr = tid >> 6;
    const float bout = b_out_g[co];
    float* outp = out + (long)b0 * MAXLEN * NCH;

    for (int st = 0; st < MAXLEN; ++st) {
        const float4* Wp4 = (const float4*)(ws + (st ? WCAT_OFF : WHH0_OFF));
        float4 acc0[4], acc1[4];
#pragma unroll
        for (int jj = 0; jj < 4; ++jj) {
            acc0[jj] = make_float4(0.f, 0.f, 0.f, 0.f);
            acc1[jj] = make_float4(0.f, 0.f, 0.f, 0.f);
        }

        // ---- GEMM over own k-slice, 4 rows x 2 units, weight-pipelined
        float4 A0 = Wp4[((kbase + 0) * 128 + up) * 2];
        float4 A1 = Wp4[((kbase + 1) * 128 + up) * 2];
        float4 A2 = Wp4[((kbase + 2) * 128 + up) * 2];
        float4 A3 = Wp4[((kbase + 3) * 128 + up) * 2];
#pragma unroll 2
        for (int k4 = 0; k4 < 16; ++k4) {
            const int k = kbase + k4 * 4;
            float4 B0 = Wp4[((k + 0) * 128 + up) * 2 + 1];
            float4 B1 = Wp4[((k + 1) * 128 + up) * 2 + 1];
            float4 B2 = Wp4[((k + 2) * 128 + up) * 2 + 1];
            float4 B3 = Wp4[((k + 3) * 128 + up) * 2 + 1];
            float4 hv0 = *(const float4*)&lds_h[ro4[0] + k];
            float4 hv1 = *(const float4*)&lds_h[ro4[1] + k];
            float4 hv2 = *(const float4*)&lds_h[ro4[2] + k];
            float4 hv3 = *(const float4*)&lds_h[ro4[3] + k];
            // unit0 half-block (uses A = weights of this k4, loaded last iter)
            fma4(acc0[0], hv0.x, A0); fma4(acc0[0], hv0.y, A1); fma4(acc0[0], hv0.z, A2); fma4(acc0[0], hv0.w, A3);
            fma4(acc0[1], hv1.x, A0); fma4(acc0[1], hv1.y, A1); fma4(acc0[1], hv1.z, A2); fma4(acc0[1], hv1.w, A3);
            fma4(acc0[2], hv2.x, A0); fma4(acc0[2], hv2.y, A1); fma4(acc0[2], hv2.z, A2); fma4(acc0[2], hv2.w, A3);
            fma4(acc0[3], hv3.x, A0); fma4(acc0[3], hv3.y, A1); fma4(acc0[3], hv3.z, A2); fma4(acc0[3], hv3.w, A3);
            // prefetch next k4's unit0 weights while unit1 half-block runs
            if (k4 < 15) {
                const int kn = k + 4;
                A0 = Wp4[((kn + 0) * 128 + up) * 2];
                A1 = Wp4[((kn + 1) * 128 + up) * 2];
                A2 = Wp4[((kn + 2) * 128 + up) * 2];
                A3 = Wp4[((kn + 3) * 128 + up) * 2];
            }
            // unit1 half-block
            fma4(acc1[0], hv0.x, B0); fma4(acc1[0], hv0.y, B1); fma4(acc1[0], hv0.z, B2); fma4(acc1[0], hv0.w, B3);
            fma4(acc1[1], hv1.x, B0); fma4(acc1[1], hv1.y, B1); fma4(acc1[1], hv1.z, B2); fma4(acc1[1], hv1.w, B3);
            fma4(acc1[2], hv2.x, B0); fma4(acc1[2], hv2.y, B1); fma4(acc1[2], hv2.z, B2); fma4(acc1[2], hv2.w, B3);
            fma4(acc1[3], hv3.x, B0); fma4(acc1[3], hv3.y, B1); fma4(acc1[3], hv3.z, B2); fma4(acc1[3], hv3.w, B3);
        }

        // ---- partials for 3 non-own rows: X = kg*3 + (jj-1); contiguous-16B conflict-free
        {
#pragma unroll
            for (int jj = 1; jj < 4; ++jj) {
                const int X = kg * 3 + (jj - 1);
                pbufv[X * 256 + col] = acc0[jj];
                pbufv[3072 + X * 256 + col] = acc1[jj];
            }
        }

        // ---- logits partial of PREVIOUS step's h (old lds_h); 4 independent chains
        if (st) {
            float l0 = 0.f, l1 = 0.f, l2 = 0.f, l3 = 0.f;
#pragma unroll 8
            for (int kk = 0; kk < 32; ++kk) {
                const float4 hval = *(const float4*)&hrow_base[4 * kk];
                l0 += hval.x * wcolT[(4 * kk + 0) * 64];
                l1 += hval.y * wcolT[(4 * kk + 1) * 64];
                l2 += hval.z * wcolT[(4 * kk + 2) * 64];
                l3 += hval.w * wcolT[(4 * kk + 3) * 64];
            }
            lbuf[tid] = (l0 + l1) + (l2 + l3);
        }

        __syncthreads();   // A: partials + logit-partials visible; all old-h reads done

        // ---- reduce own row (slot 0) + epilogue for units u0, u1
        float4 s0 = acc0[0], s1 = acc1[0];
#pragma unroll
        for (int kq = 0; kq < 4; ++kq) {
            if (kq != kg) {
                const int slot = ((kg - kq) & 3) - 1;      // 0..2
                const int X = kq * 3 + slot;
                const float4 p0 = pbufv[X * 256 + col];
                const float4 p1 = pbufv[3072 + X * 256 + col];
                s0.x += p0.x; s0.y += p0.y; s0.z += p0.z; s0.w += p0.w;
                s1.x += p1.x; s1.y += p1.y; s1.z += p1.z; s1.w += p1.w;
            }
        }
        float hn0, hn1;
        if (st == 0) {
            float r0 = sigm(s0.x + bc0_0.x), z0 = sigm(s0.y + bc0_0.y);
            hn0 = (1.f - z0) * tanh_f(binc0 + r0 * (s0.z + bc0_0.z)) + z0 * h_own0;
            float r1 = sigm(s1.x + bc0_1.x), z1 = sigm(s1.y + bc0_1.y);
            hn1 = (1.f - z1) * tanh_f(binc1 + r1 * (s1.z + bc0_1.z)) + z1 * h_own1;
        } else {
            float r0 = sigm(s0.x + bc1_0.x), z0 = sigm(s0.y + bc1_0.y);
            hn0 = (1.f - z0) * tanh_f(s0.z + bc1_0.z + r0 * (s0.w + bc1_0.w)) + z0 * h_own0;
            float r1 = sigm(s1.x + bc1_1.x), z1 = sigm(s1.y + bc1_1.y);
            hn1 = (1.f - z1) * tanh_f(s1.z + bc1_1.z + r1 * (s1.w + bc1_1.w)) + z1 * h_own1;
        }
        *(float2*)&lds_h[r_own * 256 + u0] = make_float2(hn0, hn1);
        h_own0 = hn0; h_own1 = hn1;

        // ---- combine + store previous step's logits
        if (st && tid < 512) {
            float l = lbuf[2 * tid] + lbuf[2 * tid + 1] + bout;
            outp[(long)cr * MAXLEN * NCH + (st - 1) * NCH + co] = l;
        }
        __syncthreads();   // B: new h visible
    }

    // ---- final step's logits
    {
        float l0 = 0.f, l1 = 0.f, l2 = 0.f, l3 = 0.f;
#pragma unroll 8
        for (int kk = 0; kk < 32; ++kk) {
            const float4 hval = *(const float4*)&hrow_base[4 * kk];
            l0 += hval.x * wcolT[(4 * kk + 0) * 64];
            l1 += hval.y * wcolT[(4 * kk + 1) * 64];
            l2 += hval.z * wcolT[(4 * kk + 2) * 64];
            l3 += hval.w * wcolT[(4 * kk + 3) * 64];
        }
        lbuf[tid] = (l0 + l1) + (l2 + l3);
    }
    __syncthreads();
    if (tid < 512) {
        float l = lbuf[2 * tid] + lbuf[2 * tid + 1] + bout;
        outp[(long)cr * MAXLEN * NCH + (MAXLEN - 1) * NCH + co] = l;
    }
}

extern "C" void kernel_launch(void* const* d_in, const int* in_sizes, int n_in,
                              void* d_out, int out_size, void* d_ws, size_t ws_size,
                              hipStream_t stream) {
    const float* z     = (const float*)d_in[0];
    const float* xcond = (const float*)d_in[1];
    const float* W_lh  = (const float*)d_in[2];
    const float* b_lh  = (const float*)d_in[3];
    const float* W_ih  = (const float*)d_in[4];
    const float* W_hh  = (const float*)d_in[5];
    const float* b_ih  = (const float*)d_in[6];
    const float* b_hh  = (const float*)d_in[7];
    const float* W_out = (const float*)d_in[8];
    const float* b_out = (const float*)d_in[9];
    float* out = (float*)d_out;
    float* ws  = (float*)d_ws;

    hipLaunchKernelGGL(prep_kernel, dim3(384), dim3(256), 0, stream,
                       W_lh, W_ih, W_hh, b_ih, b_hh, W_out, ws);
    hipLaunchKernelGGL(gru_persist, dim3(256), dim3(1024), 0, stream,
                       z, xcond, b_lh, b_ih, b_out, ws, out);
}